// Round 5
// baseline (225.004 us; speedup 1.0000x reference)
//
#include <hip/hip_runtime.h>
#include <hip/hip_bf16.h>

// TripletLoss batch-hard mining, B=8192, D=256.
// R5: canonical GEMM structure (m93/m97 shape) — 128x128 tile, BK=64 K-loop,
//     BOTH A and B staged in LDS via global_load_lds(16B) in read-order 1KB
//     regions; short-lived fragments only (no allocator-hostile afrag[4][8]
//     held across the loop — that caused R2-R4's scratch spill, WRITE 8-20MB).
//     Triangle grid (2080 blocks), key-encoded dual-side mining, folded finish.

constexpr int NB = 8192;
constexpr int NBT = NB / 128;                  // 64 tile-blocks per side
constexpr int NBLK = NBT * (NBT + 1) / 2;      // 2080

typedef __attribute__((ext_vector_type(8))) short bf16x8;
typedef __attribute__((ext_vector_type(4))) float f32x4;

typedef __attribute__((address_space(3))) unsigned int lds_u32;
typedef __attribute__((address_space(1))) const unsigned int g_u32;

__device__ inline void load_lds16(const unsigned short* g, unsigned short* l) {
    __builtin_amdgcn_global_load_lds((g_u32*)g, (lds_u32*)l, 16, 0, 0);
}

__device__ inline unsigned short f2bf(float v) {
    __hip_bfloat16 b = __float2bfloat16(v);
    return *reinterpret_cast<unsigned short*>(&b);
}

// key = sim + 8*min(|lr-lc|,1); pos keys in [-1,1], neg in [7,9]; diagonal
// self-pairs forced to 6.0. Encoded as uint bits of (key+2): pos [1,3],
// self 8, neg [9,11] — uint order == float order. min(enc)=hardest positive,
// max(enc)=hardest negative. ENC6 = bits of 6.0f is the validity watershed.
#define ENC6 0x40C00000u

// ---------------- Kernel 1: normalize rows -> bf16 chunk-major; init state --
// Xbt 16B-unit index u = chunk*NB + row (chunk = k/8, 32 chunks of 8 elems).
__global__ __launch_bounds__(256) void norm_kernel(const float* __restrict__ X,
                                                   unsigned short* __restrict__ Xbt,
                                                   unsigned int* minKey,
                                                   unsigned int* maxKey, int* done) {
    __shared__ float tile[32][260];
    __shared__ float psum[32][8];
    __shared__ float rscale[32];
    const int t = threadIdx.x;
    const int rb = blockIdx.x * 32;
    const int g = blockIdx.x * 256 + t;
    if (g < NB) { minKey[g] = 0xFFFFFFFFu; maxKey[g] = 0u; }
    if (g == 0) *done = 0;
    #pragma unroll
    for (int k = 0; k < 8; k++) {
        const int f = k * 256 + t;
        const int row = f >> 6, c4 = f & 63;
        const float4 v = *((const float4*)(X + (size_t)(rb + row) * 256) + c4);
        *(float4*)&tile[row][c4 * 4] = v;
    }
    __syncthreads();
    {
        const int r = t >> 3, e = t & 7;
        float s = 0.f;
        #pragma unroll
        for (int i = 0; i < 32; i++) { const float v = tile[r][e * 32 + i]; s += v * v; }
        psum[r][e] = s;
    }
    __syncthreads();
    if (t < 32) {
        float s = 0.f;
        #pragma unroll
        for (int e = 0; e < 8; e++) s += psum[t][e];
        rscale[t] = 1.0f / fmaxf(sqrtf(s), 1e-12f);
    }
    __syncthreads();
    #pragma unroll
    for (int j = 0; j < 4; j++) {
        const int idx = j * 256 + t;
        const int q = idx >> 5, r = idx & 31;
        const float sc = rscale[r];
        unsigned short tmp[8];
        #pragma unroll
        for (int e = 0; e < 8; e++) tmp[e] = f2bf(tile[r][q * 8 + e] * sc);
        *(bf16x8*)(Xbt + ((size_t)q * NB + rb + r) * 8) = *(bf16x8*)tmp;
    }
}

// ---------------- Kernel 2: symmetric Gram + mining + folded finish ---------
// Block = 128x128 tile. 4 waves in 2x2: wave w -> row-half h=w&1 (64 rows),
// col-half v=w>>1 (64 cols). K-loop kb=0..3 (BK=64): stage 32 regions of 1KB:
//   region rg<16 (A):  (ks=rg>>3, mi=rg&7): lane L holds row mi*16+(L&15),
//                      chunk kb*8+ks*4+(L>>4)   [ks = k-step of 32 within BK]
//   region rg>=16 (B): same with cols.
// Every ds_read_b128 is base + lane*16 (conflict-free, zero addr VALU).
__global__ __launch_bounds__(256) void mine_kernel(
    const unsigned short* __restrict__ Xbt, const int* __restrict__ labels,
    unsigned int* minKey, unsigned int* maxKey, int* done,
    float* __restrict__ out) {
    __shared__ unsigned short Bt[32 * 512];   // 32 KB
    __shared__ float Lrow[128], Lcol[128];
    __shared__ int ticket_s;

    // triangle decode: blockIdx.x -> (Jblk=a, Iblk<=a)
    const int tb = blockIdx.x;
    int a = (int)((sqrtf(8.0f * (float)tb + 1.0f) - 1.0f) * 0.5f);
    while ((a + 1) * (a + 2) / 2 <= tb) a++;
    while (a * (a + 1) / 2 > tb) a--;
    const int Iblk = tb - a * (a + 1) / 2;
    const int Jblk = a;
    const bool isdiag = (Iblk == Jblk);
    const int Irow0 = Iblk * 128;
    const int Jcol0 = Jblk * 128;

    const int tid = threadIdx.x;
    const int w = tid >> 6;
    const int lane = tid & 63;
    const int quad = lane >> 4;
    const int l16 = lane & 15;
    const int h = w & 1;       // row half
    const int v = w >> 1;      // col half

    if (tid < 128) Lrow[tid] = (float)labels[Irow0 + tid];
    else Lcol[tid - 128] = (float)labels[Jcol0 + tid - 128];

    f32x4 acc[4][4];
    #pragma unroll
    for (int mi = 0; mi < 4; mi++)
        #pragma unroll
        for (int ni = 0; ni < 4; ni++) acc[mi][ni] = (f32x4){0.f, 0.f, 0.f, 0.f};

    for (int kb = 0; kb < 4; kb++) {
        __syncthreads();   // protect Bt (and order Lrow/Lcol on first iter)
        #pragma unroll
        for (int s = 0; s < 8; s++) {
            const int rg = w * 8 + s;           // 0..31
            const int r2 = rg & 15;
            const int ks = r2 >> 3;
            const int ti = r2 & 7;
            const int base = (rg >> 4) ? Jcol0 : Irow0;
            const int c = kb * 8 + ks * 4 + (lane >> 4);
            const size_t u = (size_t)c * NB + base + ti * 16 + l16;
            load_lds16(Xbt + u * 8, Bt + rg * 512);
        }
        __syncthreads();   // drains vmcnt incl. global_load_lds

        #pragma unroll
        for (int ks = 0; ks < 2; ks++) {
            bf16x8 af[4], bf[4];
            #pragma unroll
            for (int i = 0; i < 4; i++) {
                af[i] = *(const bf16x8*)(Bt + (ks * 8 + h * 4 + i) * 512 + lane * 8);
                bf[i] = *(const bf16x8*)(Bt + (16 + ks * 8 + v * 4 + i) * 512 + lane * 8);
            }
            #pragma unroll
            for (int mi = 0; mi < 4; mi++)
                #pragma unroll
                for (int ni = 0; ni < 4; ni++)
                    acc[mi][ni] = __builtin_amdgcn_mfma_f32_16x16x32_bf16(
                        af[mi], bf[ni], acc[mi][ni], 0, 0, 0);
        }
    }

    // ---- mining epilogue. C/D: row = quad*4+reg, col = l16 within 16-tile.
    const bool diagwave = isdiag && (h == v);
    float flc[4], cMin[4], cMax[4];
    #pragma unroll
    for (int ni = 0; ni < 4; ni++) {
        flc[ni] = Lcol[v * 64 + ni * 16 + l16];
        cMin[ni] = 1e30f;
        cMax[ni] = -1e30f;
    }
    #pragma unroll
    for (int mi = 0; mi < 4; mi++)
        #pragma unroll
        for (int r = 0; r < 4; r++) {
            const float flr = Lrow[h * 64 + mi * 16 + quad * 4 + r];
            float rMin = 1e30f, rMax = -1e30f;
            #pragma unroll
            for (int ni = 0; ni < 4; ni++) {
                const float uu = fminf(fabsf(flr - flc[ni]), 1.0f);
                float key = fmaf(uu, 8.0f, acc[mi][ni][r]);
                if (diagwave && mi == ni)   // neutralize exact self-pair
                    key = (l16 == quad * 4 + r) ? 6.0f : key;
                rMin = fminf(rMin, key);
                rMax = fmaxf(rMax, key);
                cMin[ni] = fminf(cMin[ni], key);
                cMax[ni] = fmaxf(cMax[ni], key);
            }
            #pragma unroll
            for (int m = 1; m <= 8; m <<= 1) {
                rMin = fminf(rMin, __shfl_xor(rMin, m, 64));
                rMax = fmaxf(rMax, __shfl_xor(rMax, m, 64));
            }
            if (l16 == 0) {
                const int row = Irow0 + h * 64 + mi * 16 + quad * 4 + r;
                atomicMin(&minKey[row], __float_as_uint(rMin + 2.0f));
                atomicMax(&maxKey[row], __float_as_uint(rMax + 2.0f));
            }
        }
    if (!isdiag) {   // col-side (transpose contribution); diag blocks covered
        #pragma unroll
        for (int ni = 0; ni < 4; ni++) {
            float p = cMin[ni], n = cMax[ni];
            p = fminf(p, __shfl_xor(p, 16, 64));
            p = fminf(p, __shfl_xor(p, 32, 64));
            n = fmaxf(n, __shfl_xor(n, 16, 64));
            n = fmaxf(n, __shfl_xor(n, 32, 64));
            if (quad == 0) {
                const int col = Jcol0 + v * 64 + ni * 16 + l16;
                atomicMin(&minKey[col], __float_as_uint(p + 2.0f));
                atomicMax(&maxKey[col], __float_as_uint(n + 2.0f));
            }
        }
    }

    // ---- folded finish: last block to arrive reduces the key arrays
    __threadfence();
    __syncthreads();
    if (tid == 0) ticket_s = atomicAdd(done, 1);
    __syncthreads();
    if (ticket_s == (int)gridDim.x - 1) {
        __threadfence();
        float per = 0.f, cnt = 0.f;
        #pragma unroll
        for (int k = 0; k < NB / 256; k++) {
            const int i = k * 256 + tid;
            const unsigned int mk = minKey[i], xk = maxKey[i];
            const bool valid = (mk < ENC6) && (xk > ENC6);
            const float ps = __uint_as_float(mk) - 2.0f;    // hardest-pos sim
            const float ns = __uint_as_float(xk) - 10.0f;   // hardest-neg sim
            const float pd = fmaxf(1.0f - ps, 0.0f);
            const float nd = fmaxf(1.0f - ns, 0.0f);
            per += valid ? fmaxf(pd - nd + 1.0f, 0.0f) : 0.0f;
            cnt += valid ? 1.0f : 0.0f;
        }
        #pragma unroll
        for (int off = 32; off > 0; off >>= 1) {
            per += __shfl_down(per, off, 64);
            cnt += __shfl_down(cnt, off, 64);
        }
        __shared__ float sp[4], sc[4];
        const int wv = tid >> 6, ln = tid & 63;
        if (ln == 0) { sp[wv] = per; sc[wv] = cnt; }
        __syncthreads();
        if (tid == 0) {
            const float s = sp[0] + sp[1] + sp[2] + sp[3];
            const float c = sc[0] + sc[1] + sc[2] + sc[3];
            out[0] = (c > 0.f) ? s / fmaxf(c, 1.f) : 0.f;
        }
    }
}

// ---------------- launcher --------------------------------------------------
extern "C" void kernel_launch(void* const* d_in, const int* in_sizes, int n_in,
                              void* d_out, int out_size, void* d_ws, size_t ws_size,
                              hipStream_t stream) {
    const float* X = (const float*)d_in[0];
    const int* labels = (const int*)d_in[1];
    float* out = (float*)d_out;

    char* ws = (char*)d_ws;
    unsigned short* Xbt = (unsigned short*)ws;                    // 4 MB
    unsigned int* minKey = (unsigned int*)(ws + (size_t)4 * 1024 * 1024);
    unsigned int* maxKey = minKey + NB;
    int* done = (int*)(maxKey + NB);

    norm_kernel<<<NB / 32, 256, 0, stream>>>(X, Xbt, minKey, maxKey, done);
    mine_kernel<<<NBLK, 256, 0, stream>>>(
        (const unsigned short*)Xbt, labels, minKey, maxKey, done, out);
}

// Round 6
// 115.605 us; speedup vs baseline: 1.9463x; 1.9463x over previous
//
#include <hip/hip_runtime.h>
#include <hip/hip_bf16.h>

// TripletLoss batch-hard mining, B=8192, D=256.
// R6: R5's GEMM core, MINUS the per-block device-scope __threadfence / folded
//     finish (diagnosed as the R3-R5 killer: per-block buffer_wbl2+inv = L2
//     writeback+invalidate x gridDim -> WRITE_SIZE ∝ blocks, latency-bound).
//     Stream ordering replaces the done-counter: finish is its own tiny launch.

constexpr int NB = 8192;
constexpr int NBT = NB / 128;                  // 64 tile-blocks per side
constexpr int NBLK = NBT * (NBT + 1) / 2;      // 2080

typedef __attribute__((ext_vector_type(8))) short bf16x8;
typedef __attribute__((ext_vector_type(4))) float f32x4;

typedef __attribute__((address_space(3))) unsigned int lds_u32;
typedef __attribute__((address_space(1))) const unsigned int g_u32;

__device__ inline void load_lds16(const unsigned short* g, unsigned short* l) {
    __builtin_amdgcn_global_load_lds((g_u32*)g, (lds_u32*)l, 16, 0, 0);
}

__device__ inline unsigned short f2bf(float v) {
    __hip_bfloat16 b = __float2bfloat16(v);
    return *reinterpret_cast<unsigned short*>(&b);
}

// key = sim + 8*min(|lr-lc|,1); pos keys in [-1,1], neg in [7,9]; diagonal
// self-pairs forced to 6.0. Encoded as uint bits of (key+2): pos [1,3],
// self 8, neg [9,11] — uint order == float order. min(enc)=hardest positive,
// max(enc)=hardest negative. ENC6 = bits of 6.0f is the validity watershed.
#define ENC6 0x40C00000u

// ---------------- Kernel 1: normalize rows -> bf16 chunk-major; init state --
// Xbt 16B-unit index u = chunk*NB + row (chunk = k/8, 32 chunks of 8 elems).
__global__ __launch_bounds__(256) void norm_kernel(const float* __restrict__ X,
                                                   unsigned short* __restrict__ Xbt,
                                                   unsigned int* minKey,
                                                   unsigned int* maxKey) {
    __shared__ float tile[32][260];
    __shared__ float psum[32][8];
    __shared__ float rscale[32];
    const int t = threadIdx.x;
    const int rb = blockIdx.x * 32;
    const int g = blockIdx.x * 256 + t;
    if (g < NB) { minKey[g] = 0xFFFFFFFFu; maxKey[g] = 0u; }
    #pragma unroll
    for (int k = 0; k < 8; k++) {
        const int f = k * 256 + t;
        const int row = f >> 6, c4 = f & 63;
        const float4 v = *((const float4*)(X + (size_t)(rb + row) * 256) + c4);
        *(float4*)&tile[row][c4 * 4] = v;
    }
    __syncthreads();
    {
        const int r = t >> 3, e = t & 7;
        float s = 0.f;
        #pragma unroll
        for (int i = 0; i < 32; i++) { const float v = tile[r][e * 32 + i]; s += v * v; }
        psum[r][e] = s;
    }
    __syncthreads();
    if (t < 32) {
        float s = 0.f;
        #pragma unroll
        for (int e = 0; e < 8; e++) s += psum[t][e];
        rscale[t] = 1.0f / fmaxf(sqrtf(s), 1e-12f);
    }
    __syncthreads();
    #pragma unroll
    for (int j = 0; j < 4; j++) {
        const int idx = j * 256 + t;
        const int q = idx >> 5, r = idx & 31;
        const float sc = rscale[r];
        unsigned short tmp[8];
        #pragma unroll
        for (int e = 0; e < 8; e++) tmp[e] = f2bf(tile[r][q * 8 + e] * sc);
        *(bf16x8*)(Xbt + ((size_t)q * NB + rb + r) * 8) = *(bf16x8*)tmp;
    }
}

// ---------------- Kernel 2: symmetric Gram + mining (no fence, no finish) ---
// Block = 128x128 tile. 4 waves in 2x2: wave w -> row-half h=w&1 (64 rows),
// col-half v=w>>1 (64 cols). K-loop kb=0..3 (BK=64): stage 32 regions of 1KB:
//   region rg<16 (A):  (ks=rg>>3, ti=rg&7): lane L holds row ti*16+(L&15),
//                      chunk kb*8+ks*4+(L>>4)
//   region rg>=16 (B): same with cols.
// Every ds_read_b128 is base + lane*16 (conflict-free, zero addr VALU).
__global__ __launch_bounds__(256) void mine_kernel(
    const unsigned short* __restrict__ Xbt, const int* __restrict__ labels,
    unsigned int* minKey, unsigned int* maxKey) {
    __shared__ unsigned short Bt[32 * 512];   // 32 KB
    __shared__ float Lrow[128], Lcol[128];

    // triangle decode: blockIdx.x -> (Jblk=a, Iblk<=a)
    const int tb = blockIdx.x;
    int a = (int)((sqrtf(8.0f * (float)tb + 1.0f) - 1.0f) * 0.5f);
    while ((a + 1) * (a + 2) / 2 <= tb) a++;
    while (a * (a + 1) / 2 > tb) a--;
    const int Iblk = tb - a * (a + 1) / 2;
    const int Jblk = a;
    const bool isdiag = (Iblk == Jblk);
    const int Irow0 = Iblk * 128;
    const int Jcol0 = Jblk * 128;

    const int tid = threadIdx.x;
    const int w = tid >> 6;
    const int lane = tid & 63;
    const int quad = lane >> 4;
    const int l16 = lane & 15;
    const int h = w & 1;       // row half
    const int v = w >> 1;      // col half

    if (tid < 128) Lrow[tid] = (float)labels[Irow0 + tid];
    else Lcol[tid - 128] = (float)labels[Jcol0 + tid - 128];

    f32x4 acc[4][4];
    #pragma unroll
    for (int mi = 0; mi < 4; mi++)
        #pragma unroll
        for (int ni = 0; ni < 4; ni++) acc[mi][ni] = (f32x4){0.f, 0.f, 0.f, 0.f};

    for (int kb = 0; kb < 4; kb++) {
        __syncthreads();   // protect Bt (and order Lrow/Lcol on first iter)
        #pragma unroll
        for (int s = 0; s < 8; s++) {
            const int rg = w * 8 + s;           // 0..31
            const int r2 = rg & 15;
            const int ks = r2 >> 3;
            const int ti = r2 & 7;
            const int base = (rg >> 4) ? Jcol0 : Irow0;
            const int c = kb * 8 + ks * 4 + (lane >> 4);
            const size_t u = (size_t)c * NB + base + ti * 16 + l16;
            load_lds16(Xbt + u * 8, Bt + rg * 512);
        }
        __syncthreads();   // drains vmcnt incl. global_load_lds

        #pragma unroll
        for (int ks = 0; ks < 2; ks++) {
            bf16x8 af[4], bf[4];
            #pragma unroll
            for (int i = 0; i < 4; i++) {
                af[i] = *(const bf16x8*)(Bt + (ks * 8 + h * 4 + i) * 512 + lane * 8);
                bf[i] = *(const bf16x8*)(Bt + (16 + ks * 8 + v * 4 + i) * 512 + lane * 8);
            }
            #pragma unroll
            for (int mi = 0; mi < 4; mi++)
                #pragma unroll
                for (int ni = 0; ni < 4; ni++)
                    acc[mi][ni] = __builtin_amdgcn_mfma_f32_16x16x32_bf16(
                        af[mi], bf[ni], acc[mi][ni], 0, 0, 0);
        }
    }

    // ---- mining epilogue. C/D: row = quad*4+reg, col = l16 within 16-tile.
    const bool diagwave = isdiag && (h == v);
    float flc[4], cMin[4], cMax[4];
    #pragma unroll
    for (int ni = 0; ni < 4; ni++) {
        flc[ni] = Lcol[v * 64 + ni * 16 + l16];
        cMin[ni] = 1e30f;
        cMax[ni] = -1e30f;
    }
    #pragma unroll
    for (int mi = 0; mi < 4; mi++)
        #pragma unroll
        for (int r = 0; r < 4; r++) {
            const float flr = Lrow[h * 64 + mi * 16 + quad * 4 + r];
            float rMin = 1e30f, rMax = -1e30f;
            #pragma unroll
            for (int ni = 0; ni < 4; ni++) {
                const float uu = fminf(fabsf(flr - flc[ni]), 1.0f);
                float key = fmaf(uu, 8.0f, acc[mi][ni][r]);
                if (diagwave && mi == ni)   // neutralize exact self-pair
                    key = (l16 == quad * 4 + r) ? 6.0f : key;
                rMin = fminf(rMin, key);
                rMax = fmaxf(rMax, key);
                cMin[ni] = fminf(cMin[ni], key);
                cMax[ni] = fmaxf(cMax[ni], key);
            }
            #pragma unroll
            for (int m = 1; m <= 8; m <<= 1) {
                rMin = fminf(rMin, __shfl_xor(rMin, m, 64));
                rMax = fmaxf(rMax, __shfl_xor(rMax, m, 64));
            }
            if (l16 == 0) {
                const int row = Irow0 + h * 64 + mi * 16 + quad * 4 + r;
                atomicMin(&minKey[row], __float_as_uint(rMin + 2.0f));
                atomicMax(&maxKey[row], __float_as_uint(rMax + 2.0f));
            }
        }
    if (!isdiag) {   // col-side (transpose contribution); diag blocks covered
        #pragma unroll
        for (int ni = 0; ni < 4; ni++) {
            float p = cMin[ni], n = cMax[ni];
            p = fminf(p, __shfl_xor(p, 16, 64));
            p = fminf(p, __shfl_xor(p, 32, 64));
            n = fmaxf(n, __shfl_xor(n, 16, 64));
            n = fmaxf(n, __shfl_xor(n, 32, 64));
            if (quad == 0) {
                const int col = Jcol0 + v * 64 + ni * 16 + l16;
                atomicMin(&minKey[col], __float_as_uint(p + 2.0f));
                atomicMax(&maxKey[col], __float_as_uint(n + 2.0f));
            }
        }
    }
}

// ---------------- Kernel 3: finish (1 block; stream order = sync) -----------
__global__ __launch_bounds__(1024) void finish_kernel(
    const unsigned int* __restrict__ minKey, const unsigned int* __restrict__ maxKey,
    float* __restrict__ out) {
    const int tid = threadIdx.x;
    float per = 0.f, cnt = 0.f;
    #pragma unroll
    for (int k = 0; k < NB / 1024; k++) {
        const int i = k * 1024 + tid;
        const unsigned int mk = minKey[i], xk = maxKey[i];
        const bool valid = (mk < ENC6) && (xk > ENC6);
        const float ps = __uint_as_float(mk) - 2.0f;    // hardest-pos sim
        const float ns = __uint_as_float(xk) - 10.0f;   // hardest-neg sim
        const float pd = fmaxf(1.0f - ps, 0.0f);
        const float nd = fmaxf(1.0f - ns, 0.0f);
        per += valid ? fmaxf(pd - nd + 1.0f, 0.0f) : 0.0f;
        cnt += valid ? 1.0f : 0.0f;
    }
    #pragma unroll
    for (int off = 32; off > 0; off >>= 1) {
        per += __shfl_down(per, off, 64);
        cnt += __shfl_down(cnt, off, 64);
    }
    __shared__ float sp[16], sc[16];
    const int wv = tid >> 6, ln = tid & 63;
    if (ln == 0) { sp[wv] = per; sc[wv] = cnt; }
    __syncthreads();
    if (tid == 0) {
        float s = 0.f, c = 0.f;
        #pragma unroll
        for (int i = 0; i < 16; i++) { s += sp[i]; c += sc[i]; }
        out[0] = (c > 0.f) ? s / fmaxf(c, 1.f) : 0.f;
    }
}

// ---------------- launcher --------------------------------------------------
extern "C" void kernel_launch(void* const* d_in, const int* in_sizes, int n_in,
                              void* d_out, int out_size, void* d_ws, size_t ws_size,
                              hipStream_t stream) {
    const float* X = (const float*)d_in[0];
    const int* labels = (const int*)d_in[1];
    float* out = (float*)d_out;

    char* ws = (char*)d_ws;
    unsigned short* Xbt = (unsigned short*)ws;                    // 4 MB
    unsigned int* minKey = (unsigned int*)(ws + (size_t)4 * 1024 * 1024);
    unsigned int* maxKey = minKey + NB;

    norm_kernel<<<NB / 32, 256, 0, stream>>>(X, Xbt, minKey, maxKey);
    mine_kernel<<<NBLK, 256, 0, stream>>>(
        (const unsigned short*)Xbt, labels, minKey, maxKey);
    finish_kernel<<<1, 1024, 0, stream>>>(minKey, maxKey, out);
}